// Round 12
// baseline (308.480 us; speedup 1.0000x reference)
//
#include <hip/hip_runtime.h>
#include <math.h>

#define EMB 128
#define HIDN 256

typedef _Float16 half8 __attribute__((ext_vector_type(8)));
typedef _Float16 half4 __attribute__((ext_vector_type(4)));
typedef float f32x4 __attribute__((ext_vector_type(4)));
typedef unsigned short u16;

// ---------------- fused prep: f32->f16 + W granule packing + hist ----------------

__device__ __forceinline__ void pack_w_one(const float* __restrict__ W, _Float16* __restrict__ Wg,
                                           int K, int N, int i) {
    if (i < (K / 8) * N) {
        int j = i / N, n = i - j * N;
        half8 h;
#pragma unroll
        for (int q = 0; q < 8; ++q) h[q] = (_Float16)W[(size_t)(j * 8 + q) * N + n];
        *reinterpret_cast<half8*>(Wg + (size_t)i * 8) = h;
    }
}

__global__ void prep_kernel(const int* __restrict__ dst, int E, int* __restrict__ cur,
                            const float* __restrict__ emb, _Float16* __restrict__ buf0, int n8,
                            const float* __restrict__ W1, _Float16* __restrict__ Wg1,
                            const float* __restrict__ W2, _Float16* __restrict__ Wg2,
                            const float* __restrict__ W3, _Float16* __restrict__ Wg3,
                            int bCvtEnd, int bHistEnd, int bW1End, int bW2End, int bW3End) {
    const int b = blockIdx.x;
    const int t = threadIdx.x;
    if (b < bCvtEnd) {
        int i = b * 256 + t;
        if (i < n8) {
            const float4 v0 = *reinterpret_cast<const float4*>(emb + (size_t)i * 8);
            const float4 v1 = *reinterpret_cast<const float4*>(emb + (size_t)i * 8 + 4);
            half8 h;
            h[0] = (_Float16)v0.x; h[1] = (_Float16)v0.y;
            h[2] = (_Float16)v0.z; h[3] = (_Float16)v0.w;
            h[4] = (_Float16)v1.x; h[5] = (_Float16)v1.y;
            h[6] = (_Float16)v1.z; h[7] = (_Float16)v1.w;
            *reinterpret_cast<half8*>(buf0 + (size_t)i * 8) = h;
        }
    } else if (b < bHistEnd) {
        int i = (b - bCvtEnd) * 256 + t;
        if (i < E) atomicAdd(&cur[dst[i]], 1);
    } else if (b < bW1End) {
        pack_w_one(W1, Wg1, EMB, HIDN, (b - bHistEnd) * 256 + t);
    } else if (b < bW2End) {
        pack_w_one(W2, Wg2, HIDN, HIDN, (b - bW1End) * 256 + t);
    } else if (b < bW3End) {
        pack_w_one(W3, Wg3, HIDN, EMB, (b - bW2End) * 256 + t);
    }
}

// ---------------- hierarchical scan (2 kernels) ----------------

__global__ void scan_partial(const int* __restrict__ cnt, int* __restrict__ partials, int Nn) {
    __shared__ int red[256];
    const int b = blockIdx.x, t = threadIdx.x;
    const int base = b * 1024 + t * 4;
    int s = 0;
#pragma unroll
    for (int i = 0; i < 4; ++i)
        if (base + i < Nn) s += cnt[base + i];
    red[t] = s;
    __syncthreads();
    for (int d = 128; d > 0; d >>= 1) {
        if (t < d) red[t] += red[t + d];
        __syncthreads();
    }
    if (t == 0) partials[b] = red[0];
}

__global__ void scan_apply(const int* __restrict__ cnt, const int* __restrict__ partials,
                           int nB, int* __restrict__ off, int* __restrict__ cur, int Nn, int E) {
    __shared__ int tsum[256];
    __shared__ int sbase;
    const int b = blockIdx.x, t = threadIdx.x;
    if (t < 64) {
        int v = (t < b && t < nB) ? partials[t] : 0;
#pragma unroll
        for (int m = 1; m < 64; m <<= 1) v += __shfl_xor(v, m);
        if (t == 0) sbase = v;
    }
    const int base = b * 1024 + t * 4;
    int c[4];
#pragma unroll
    for (int i = 0; i < 4; ++i) c[i] = (base + i < Nn) ? cnt[base + i] : 0;
    int s = c[0] + c[1] + c[2] + c[3];
    tsum[t] = s;
    __syncthreads();
    for (int d = 1; d < 256; d <<= 1) {
        int v = (t >= d) ? tsum[t - d] : 0;
        __syncthreads();
        tsum[t] += v;
        __syncthreads();
    }
    int run = sbase + ((t == 0) ? 0 : tsum[t - 1]);
#pragma unroll
    for (int i = 0; i < 4; ++i) {
        int idx = base + i;
        if (idx < Nn) {
            off[idx] = run;
            cur[idx] = run;
            run += c[i];
        }
    }
    if (b == 0 && t == 0) off[Nn] = E;
}

// Nn < 65536 -> u16 neighbor indices
__global__ void scatter_kernel(const int* __restrict__ src, const int* __restrict__ dst,
                               int E, int* __restrict__ cur, u16* __restrict__ sorted) {
    int i = blockIdx.x * blockDim.x + threadIdx.x;
    if (i < E) {
        int d = dst[i];
        int p = atomicAdd(&cur[d], 1);
        sorted[p] = (u16)src[i];
    }
}

// ---------------- segment-max + self-add -> MFMA granule layout ----------------
// One wave per node (block = 4 waves = 4 nodes). NG = 512/K edge streams.
// 8 clamped loads into named registers (dup slots are L1 same-line hits; max
// idempotent). xg stores are NONTEMPORAL: xg is stream-read exactly once by
// gemm_g, and keeping it out of L2 preserves L2 for the random x gather.

template <int K>
__global__ __launch_bounds__(256) void segmax_g(
    const _Float16* __restrict__ x, const int* __restrict__ off,
    const u16* __restrict__ sorted, _Float16* __restrict__ xg, int Nn)
{
    constexpr int NG = 512 / K;        // 2 for K=256, 4 for K=128
    constexpr int LPR = 64 / NG;       // lanes per row
    __shared__ _Float16 sm[4][K];

    const int wave = threadIdx.x >> 6;
    const int lane = threadIdx.x & 63;
    const int node0 = blockIdx.x * 4;
    const int node = node0 + wave;

    if (node < Nn) {
        const int g = lane / LPR;
        const int colh = (lane % LPR) * 8;
        const int beg = off[node];
        const int end = off[node + 1];
        const _Float16* xcol = x + colh;

        half8 acc;
#pragma unroll
        for (int i = 0; i < 8; ++i) acc[i] = (_Float16)(-INFINITY);

        const int base = beg + g;
        const int cnt0 = end - base;
        if (cnt0 > 0) {
            const int m = (cnt0 + NG - 1) / NG;
            const int mm = m - 1;
            half8 v[8];
#pragma unroll
            for (int i = 0; i < 8; ++i) {
                const int ii = (i < mm) ? i : mm;
                const int s = (int)sorted[base + ii * NG];
                v[i] = *reinterpret_cast<const half8*>(xcol + (size_t)s * K);
            }
            for (int i = 8; i < m; ++i) {
                const int s = (int)sorted[base + i * NG];
                half8 w = *reinterpret_cast<const half8*>(xcol + (size_t)s * K);
                acc = __builtin_elementwise_max(acc, w);
            }
            v[0] = __builtin_elementwise_max(v[0], v[4]);
            v[1] = __builtin_elementwise_max(v[1], v[5]);
            v[2] = __builtin_elementwise_max(v[2], v[6]);
            v[3] = __builtin_elementwise_max(v[3], v[7]);
            v[0] = __builtin_elementwise_max(v[0], v[2]);
            v[1] = __builtin_elementwise_max(v[1], v[3]);
            acc  = __builtin_elementwise_max(acc, __builtin_elementwise_max(v[0], v[1]));
        }

        union U { half8 h; int i[4]; };
        if (NG == 4) {
            U a, b; a.h = acc;
#pragma unroll
            for (int k = 0; k < 4; ++k) b.i[k] = __shfl_xor(a.i[k], 16);
            acc = __builtin_elementwise_max(a.h, b.h);
        }
        {
            U a, b; a.h = acc;
#pragma unroll
            for (int k = 0; k < 4; ++k) b.i[k] = __shfl_xor(a.i[k], 32);
            acc = __builtin_elementwise_max(a.h, b.h);
        }

        if (g == 0) {
            const bool hasEdges = (end > beg);
            half8 xv = *reinterpret_cast<const half8*>(x + (size_t)node * K + colh);
            half8 o;
#pragma unroll
            for (int i = 0; i < 8; ++i)
                o[i] = (_Float16)((float)xv[i] + (hasEdges ? (float)acc[i] : 0.0f));
            *reinterpret_cast<half8*>(&sm[wave][colh]) = o;
        }
    }
    __syncthreads();

    // coalesced nontemporal granule store: threads 4j..4j+3 write one 64B line.
    const int t = threadIdx.x;
    if (t < 4 * (K / 8)) {
        const int j = t >> 2, nd = t & 3;
        const int node2 = node0 + nd;
        if (node2 < Nn) {
            half8 o2 = *reinterpret_cast<half8*>(&sm[nd][j * 8]);
            size_t gidx = ((size_t)(node2 >> 6) * (K / 8) + j) * 64 + (node2 & 63);
            __builtin_nontemporal_store(o2, reinterpret_cast<half8*>(xg + gidx * 8));
        }
    }
}

// ---------------- LDS-free MFMA GEMM from granule layout ----------------

template <int K, int N, int RB, int CB, int OUT_F32, int RELU>
__global__ __launch_bounds__(256) void gemm_g(
    const _Float16* __restrict__ xg, const _Float16* __restrict__ Wg,
    const float* __restrict__ bias, void* __restrict__ C, int Nn)
{
    const int wave = threadIdx.x >> 6;
    const int lane = threadIdx.x & 63;
    const int wr = wave / CB, wc = wave % CB;
    const int rowTile = blockIdx.x * RB + wr;
    const int node0 = rowTile * 64;
    const int r  = lane & 15;
    const int gq = lane >> 4;
    const int cb = wc * 64;

    f32x4 acc[4][4];
#pragma unroll
    for (int mi = 0; mi < 4; ++mi)
#pragma unroll
        for (int ni = 0; ni < 4; ++ni) acc[mi][ni] = (f32x4){0.f, 0.f, 0.f, 0.f};

    const _Float16* Ab = xg + (size_t)rowTile * K * 64;

    for (int k0 = 0; k0 < K; k0 += 32) {
        const int jb = (k0 >> 3) + gq;
        half8 aF[4], bF[4];
#pragma unroll
        for (int mi = 0; mi < 4; ++mi)
            aF[mi] = *reinterpret_cast<const half8*>(Ab + (size_t)((jb << 6) + mi * 16 + r) * 8);
#pragma unroll
        for (int ni = 0; ni < 4; ++ni)
            bF[ni] = *reinterpret_cast<const half8*>(Wg + ((size_t)jb * N + cb + ni * 16 + r) * 8);
#pragma unroll
        for (int mi = 0; mi < 4; ++mi)
#pragma unroll
            for (int ni = 0; ni < 4; ++ni)
                acc[mi][ni] = __builtin_amdgcn_mfma_f32_16x16x32_f16(aF[mi], bF[ni], acc[mi][ni], 0, 0, 0);
    }

#pragma unroll
    for (int ni = 0; ni < 4; ++ni) {
        int colC = cb + ni * 16 + r;
        float bv = bias[colC];
#pragma unroll
        for (int mi = 0; mi < 4; ++mi) {
#pragma unroll
            for (int q = 0; q < 4; ++q) {
                int row = node0 + mi * 16 + (gq << 2) + q;
                if (row < Nn) {
                    float v = acc[mi][ni][q] + bv;
                    if (RELU) v = fmaxf(v, 0.f);
                    if (OUT_F32) {
                        // final output: never re-read -> nontemporal
                        __builtin_nontemporal_store(v, (float*)C + (size_t)row * N + colC);
                    } else {
                        ((_Float16*)C)[(size_t)row * N + colC] = (_Float16)v;
                    }
                }
            }
        }
    }
}

// ---------------- launch ----------------

extern "C" void kernel_launch(void* const* d_in, const int* in_sizes, int n_in,
                              void* d_out, int out_size, void* d_ws, size_t ws_size,
                              hipStream_t stream) {
    const int*   src = (const int*)d_in[0];
    const int*   dst = (const int*)d_in[1];
    const float* emb = (const float*)d_in[2];
    const float* W1  = (const float*)d_in[3];
    const float* b1  = (const float*)d_in[4];
    const float* W2  = (const float*)d_in[5];
    const float* b2  = (const float*)d_in[6];
    const float* W3  = (const float*)d_in[7];
    const float* b3  = (const float*)d_in[8];
    float* out = (float*)d_out;

    const int E  = in_sizes[0];
    const int Nn = in_sizes[2] / EMB;
    const int nTiles = (Nn + 63) / 64;

    char* ws = (char*)d_ws;
    auto align256 = [](size_t x) { return (x + 255) & ~(size_t)255; };
    size_t p = 0;
    int* off      = (int*)(ws + p); p = align256(p + (size_t)(Nn + 1) * 4);
    int* cur      = (int*)(ws + p); p = align256(p + (size_t)(Nn + 1) * 4);
    int* partials = (int*)(ws + p); p = align256(p + 256 * 4);
    u16* sorted   = (u16*)(ws + p); p = align256(p + (size_t)E * 2);
    _Float16* buf0 = (_Float16*)(ws + p); p = align256(p + (size_t)Nn * HIDN * 2);
    _Float16* buf1 = (_Float16*)(ws + p); p = align256(p + (size_t)Nn * HIDN * 2);
    _Float16* xg   = (_Float16*)(ws + p); p = align256(p + (size_t)(nTiles + 2) * 64 * HIDN * 2);
    _Float16* Wg1  = (_Float16*)(ws + p); p = align256(p + (size_t)EMB * HIDN * 2);
    _Float16* Wg2  = (_Float16*)(ws + p); p = align256(p + (size_t)HIDN * HIDN * 2);
    _Float16* Wg3  = (_Float16*)(ws + p); p = align256(p + (size_t)HIDN * EMB * 2);

    // ---- zero counters, then fused prep (cvt + hist + W packs) ----
    hipMemsetAsync(cur, 0, (size_t)Nn * 4, stream);
    const int n8 = Nn * EMB / 8;
    const int bCvtEnd  = (n8 + 255) / 256;
    const int bHistEnd = bCvtEnd + (E + 255) / 256;
    const int bW1End   = bHistEnd + (EMB / 8 * HIDN + 255) / 256;
    const int bW2End   = bW1End + (HIDN / 8 * HIDN + 255) / 256;
    const int bW3End   = bW2End + (HIDN / 8 * EMB + 255) / 256;
    prep_kernel<<<bW3End, 256, 0, stream>>>(dst, E, cur, emb, buf0, n8,
                                            W1, Wg1, W2, Wg2, W3, Wg3,
                                            bCvtEnd, bHistEnd, bW1End, bW2End, bW3End);

    // ---- CSR scan + scatter ----
    const int nScanBlocks = (Nn + 1023) / 1024;   // <= 64 supported by scan_apply
    scan_partial<<<nScanBlocks, 256, 0, stream>>>(cur, partials, Nn);
    scan_apply<<<nScanBlocks, 256, 0, stream>>>(cur, partials, nScanBlocks, off, cur, Nn, E);
    scatter_kernel<<<(E + 255) / 256, 256, 0, stream>>>(src, dst, E, cur, sorted);

    const int segBlocks = (Nn + 3) / 4;

    // ---- Layer 1: K=128 -> N=256, relu ----
    segmax_g<128><<<segBlocks, 256, 0, stream>>>(buf0, off, sorted, xg, Nn);
    gemm_g<128, 256, 1, 4, 0, 1><<<nTiles, 256, 0, stream>>>(xg, Wg1, b1, buf1, Nn);

    // ---- Layer 2: K=256 -> N=256, relu ----
    segmax_g<256><<<segBlocks, 256, 0, stream>>>(buf1, off, sorted, xg, Nn);
    gemm_g<256, 256, 1, 4, 0, 1><<<nTiles, 256, 0, stream>>>(xg, Wg2, b2, buf0, Nn);

    // ---- Layer 3: K=256 -> N=128, no relu, f32 out ----
    segmax_g<256><<<segBlocks, 256, 0, stream>>>(buf0, off, sorted, xg, Nn);
    gemm_g<256, 128, 2, 2, 1, 0><<<(nTiles + 1) / 2, 256, 0, stream>>>(xg, Wg3, b3, out, Nn);
}

// Round 13
// 293.774 us; speedup vs baseline: 1.0501x; 1.0501x over previous
//
#include <hip/hip_runtime.h>
#include <math.h>

#define EMB 128
#define HIDN 256

typedef _Float16 half8 __attribute__((ext_vector_type(8)));
typedef _Float16 half4 __attribute__((ext_vector_type(4)));
typedef float f32x4 __attribute__((ext_vector_type(4)));
typedef unsigned short u16;

// ---------------- fused prep: f32->f16 + W granule packing + hist ----------------

__device__ __forceinline__ void pack_w_one(const float* __restrict__ W, _Float16* __restrict__ Wg,
                                           int K, int N, int i) {
    if (i < (K / 8) * N) {
        int j = i / N, n = i - j * N;
        half8 h;
#pragma unroll
        for (int q = 0; q < 8; ++q) h[q] = (_Float16)W[(size_t)(j * 8 + q) * N + n];
        *reinterpret_cast<half8*>(Wg + (size_t)i * 8) = h;
    }
}

__global__ void prep_kernel(const int* __restrict__ dst, int E, int* __restrict__ cur,
                            const float* __restrict__ emb, _Float16* __restrict__ buf0, int n8,
                            const float* __restrict__ W1, _Float16* __restrict__ Wg1,
                            const float* __restrict__ W2, _Float16* __restrict__ Wg2,
                            const float* __restrict__ W3, _Float16* __restrict__ Wg3,
                            int bCvtEnd, int bHistEnd, int bW1End, int bW2End, int bW3End) {
    const int b = blockIdx.x;
    const int t = threadIdx.x;
    if (b < bCvtEnd) {
        int i = b * 256 + t;
        if (i < n8) {
            const float4 v0 = *reinterpret_cast<const float4*>(emb + (size_t)i * 8);
            const float4 v1 = *reinterpret_cast<const float4*>(emb + (size_t)i * 8 + 4);
            half8 h;
            h[0] = (_Float16)v0.x; h[1] = (_Float16)v0.y;
            h[2] = (_Float16)v0.z; h[3] = (_Float16)v0.w;
            h[4] = (_Float16)v1.x; h[5] = (_Float16)v1.y;
            h[6] = (_Float16)v1.z; h[7] = (_Float16)v1.w;
            *reinterpret_cast<half8*>(buf0 + (size_t)i * 8) = h;
        }
    } else if (b < bHistEnd) {
        int i = (b - bCvtEnd) * 256 + t;
        if (i < E) atomicAdd(&cur[dst[i]], 1);
    } else if (b < bW1End) {
        pack_w_one(W1, Wg1, EMB, HIDN, (b - bHistEnd) * 256 + t);
    } else if (b < bW2End) {
        pack_w_one(W2, Wg2, HIDN, HIDN, (b - bW1End) * 256 + t);
    } else if (b < bW3End) {
        pack_w_one(W3, Wg3, HIDN, EMB, (b - bW2End) * 256 + t);
    }
}

// ---------------- hierarchical scan (2 kernels) ----------------

__global__ void scan_partial(const int* __restrict__ cnt, int* __restrict__ partials, int Nn) {
    __shared__ int red[256];
    const int b = blockIdx.x, t = threadIdx.x;
    const int base = b * 1024 + t * 4;
    int s = 0;
#pragma unroll
    for (int i = 0; i < 4; ++i)
        if (base + i < Nn) s += cnt[base + i];
    red[t] = s;
    __syncthreads();
    for (int d = 128; d > 0; d >>= 1) {
        if (t < d) red[t] += red[t + d];
        __syncthreads();
    }
    if (t == 0) partials[b] = red[0];
}

__global__ void scan_apply(const int* __restrict__ cnt, const int* __restrict__ partials,
                           int nB, int* __restrict__ off, int* __restrict__ cur, int Nn, int E) {
    __shared__ int tsum[256];
    __shared__ int sbase;
    const int b = blockIdx.x, t = threadIdx.x;
    if (t < 64) {
        int v = (t < b && t < nB) ? partials[t] : 0;
#pragma unroll
        for (int m = 1; m < 64; m <<= 1) v += __shfl_xor(v, m);
        if (t == 0) sbase = v;
    }
    const int base = b * 1024 + t * 4;
    int c[4];
#pragma unroll
    for (int i = 0; i < 4; ++i) c[i] = (base + i < Nn) ? cnt[base + i] : 0;
    int s = c[0] + c[1] + c[2] + c[3];
    tsum[t] = s;
    __syncthreads();
    for (int d = 1; d < 256; d <<= 1) {
        int v = (t >= d) ? tsum[t - d] : 0;
        __syncthreads();
        tsum[t] += v;
        __syncthreads();
    }
    int run = sbase + ((t == 0) ? 0 : tsum[t - 1]);
#pragma unroll
    for (int i = 0; i < 4; ++i) {
        int idx = base + i;
        if (idx < Nn) {
            off[idx] = run;
            cur[idx] = run;
            run += c[i];
        }
    }
    if (b == 0 && t == 0) off[Nn] = E;
}

// Nn < 65536 -> u16 neighbor indices
__global__ void scatter_kernel(const int* __restrict__ src, const int* __restrict__ dst,
                               int E, int* __restrict__ cur, u16* __restrict__ sorted) {
    int i = blockIdx.x * blockDim.x + threadIdx.x;
    if (i < E) {
        int d = dst[i];
        int p = atomicAdd(&cur[d], 1);
        sorted[p] = (u16)src[i];
    }
}

// ---------------- segment-max + self-add -> MFMA granule layout ----------------
// One wave per node (block = 4 waves = 4 nodes). NG = 512/K edge streams.
// 8 clamped loads into named registers (dup slots are L1 same-line hits; max
// idempotent) -> 8 misses in flight per wave. Rare deg > 8*NG tail loop.

template <int K>
__global__ __launch_bounds__(256) void segmax_g(
    const _Float16* __restrict__ x, const int* __restrict__ off,
    const u16* __restrict__ sorted, _Float16* __restrict__ xg, int Nn)
{
    constexpr int NG = 512 / K;        // 2 for K=256, 4 for K=128
    constexpr int LPR = 64 / NG;       // lanes per row
    __shared__ _Float16 sm[4][K];

    const int wave = threadIdx.x >> 6;
    const int lane = threadIdx.x & 63;
    const int node0 = blockIdx.x * 4;
    const int node = node0 + wave;

    if (node < Nn) {
        const int g = lane / LPR;
        const int colh = (lane % LPR) * 8;
        const int beg = off[node];
        const int end = off[node + 1];
        const _Float16* xcol = x + colh;

        half8 acc;
#pragma unroll
        for (int i = 0; i < 8; ++i) acc[i] = (_Float16)(-INFINITY);

        const int base = beg + g;
        const int cnt0 = end - base;
        if (cnt0 > 0) {
            const int m = (cnt0 + NG - 1) / NG;
            const int mm = m - 1;
            half8 v[8];
#pragma unroll
            for (int i = 0; i < 8; ++i) {
                const int ii = (i < mm) ? i : mm;
                const int s = (int)sorted[base + ii * NG];
                v[i] = *reinterpret_cast<const half8*>(xcol + (size_t)s * K);
            }
            for (int i = 8; i < m; ++i) {
                const int s = (int)sorted[base + i * NG];
                half8 w = *reinterpret_cast<const half8*>(xcol + (size_t)s * K);
                acc = __builtin_elementwise_max(acc, w);
            }
            v[0] = __builtin_elementwise_max(v[0], v[4]);
            v[1] = __builtin_elementwise_max(v[1], v[5]);
            v[2] = __builtin_elementwise_max(v[2], v[6]);
            v[3] = __builtin_elementwise_max(v[3], v[7]);
            v[0] = __builtin_elementwise_max(v[0], v[2]);
            v[1] = __builtin_elementwise_max(v[1], v[3]);
            acc  = __builtin_elementwise_max(acc, __builtin_elementwise_max(v[0], v[1]));
        }

        union U { half8 h; int i[4]; };
        if (NG == 4) {
            U a, b; a.h = acc;
#pragma unroll
            for (int k = 0; k < 4; ++k) b.i[k] = __shfl_xor(a.i[k], 16);
            acc = __builtin_elementwise_max(a.h, b.h);
        }
        {
            U a, b; a.h = acc;
#pragma unroll
            for (int k = 0; k < 4; ++k) b.i[k] = __shfl_xor(a.i[k], 32);
            acc = __builtin_elementwise_max(a.h, b.h);
        }

        if (g == 0) {
            const bool hasEdges = (end > beg);
            half8 xv = *reinterpret_cast<const half8*>(x + (size_t)node * K + colh);
            half8 o;
#pragma unroll
            for (int i = 0; i < 8; ++i)
                o[i] = (_Float16)((float)xv[i] + (hasEdges ? (float)acc[i] : 0.0f));
            *reinterpret_cast<half8*>(&sm[wave][colh]) = o;
        }
    }
    __syncthreads();

    // coalesced granule store: threads 4j..4j+3 write one full 64B line.
    const int t = threadIdx.x;
    if (t < 4 * (K / 8)) {
        const int j = t >> 2, nd = t & 3;
        const int node2 = node0 + nd;
        if (node2 < Nn) {
            half8 o2 = *reinterpret_cast<half8*>(&sm[nd][j * 8]);
            size_t gidx = ((size_t)(node2 >> 6) * (K / 8) + j) * 64 + (node2 & 63);
            *reinterpret_cast<half8*>(xg + gidx * 8) = o2;
        }
    }
}

// ---------------- LDS-free MFMA GEMM from granule layout ----------------

template <int K, int N, int RB, int CB, int OUT_F32, int RELU>
__global__ __launch_bounds__(256) void gemm_g(
    const _Float16* __restrict__ xg, const _Float16* __restrict__ Wg,
    const float* __restrict__ bias, void* __restrict__ C, int Nn)
{
    const int wave = threadIdx.x >> 6;
    const int lane = threadIdx.x & 63;
    const int wr = wave / CB, wc = wave % CB;
    const int rowTile = blockIdx.x * RB + wr;
    const int node0 = rowTile * 64;
    const int r  = lane & 15;
    const int gq = lane >> 4;
    const int cb = wc * 64;

    f32x4 acc[4][4];
#pragma unroll
    for (int mi = 0; mi < 4; ++mi)
#pragma unroll
        for (int ni = 0; ni < 4; ++ni) acc[mi][ni] = (f32x4){0.f, 0.f, 0.f, 0.f};

    const _Float16* Ab = xg + (size_t)rowTile * K * 64;

    for (int k0 = 0; k0 < K; k0 += 32) {
        const int jb = (k0 >> 3) + gq;
        half8 aF[4], bF[4];
#pragma unroll
        for (int mi = 0; mi < 4; ++mi)
            aF[mi] = *reinterpret_cast<const half8*>(Ab + (size_t)((jb << 6) + mi * 16 + r) * 8);
#pragma unroll
        for (int ni = 0; ni < 4; ++ni)
            bF[ni] = *reinterpret_cast<const half8*>(Wg + ((size_t)jb * N + cb + ni * 16 + r) * 8);
#pragma unroll
        for (int mi = 0; mi < 4; ++mi)
#pragma unroll
            for (int ni = 0; ni < 4; ++ni)
                acc[mi][ni] = __builtin_amdgcn_mfma_f32_16x16x32_f16(aF[mi], bF[ni], acc[mi][ni], 0, 0, 0);
    }

#pragma unroll
    for (int ni = 0; ni < 4; ++ni) {
        int colC = cb + ni * 16 + r;
        float bv = bias[colC];
#pragma unroll
        for (int mi = 0; mi < 4; ++mi) {
#pragma unroll
            for (int q = 0; q < 4; ++q) {
                int row = node0 + mi * 16 + (gq << 2) + q;
                if (row < Nn) {
                    float v = acc[mi][ni][q] + bv;
                    if (RELU) v = fmaxf(v, 0.f);
                    if (OUT_F32) ((float*)C)[(size_t)row * N + colC] = v;
                    else         ((_Float16*)C)[(size_t)row * N + colC] = (_Float16)v;
                }
            }
        }
    }
}

// ---------------- launch ----------------

extern "C" void kernel_launch(void* const* d_in, const int* in_sizes, int n_in,
                              void* d_out, int out_size, void* d_ws, size_t ws_size,
                              hipStream_t stream) {
    const int*   src = (const int*)d_in[0];
    const int*   dst = (const int*)d_in[1];
    const float* emb = (const float*)d_in[2];
    const float* W1  = (const float*)d_in[3];
    const float* b1  = (const float*)d_in[4];
    const float* W2  = (const float*)d_in[5];
    const float* b2  = (const float*)d_in[6];
    const float* W3  = (const float*)d_in[7];
    const float* b3  = (const float*)d_in[8];
    float* out = (float*)d_out;

    const int E  = in_sizes[0];
    const int Nn = in_sizes[2] / EMB;
    const int nTiles = (Nn + 63) / 64;

    char* ws = (char*)d_ws;
    auto align256 = [](size_t x) { return (x + 255) & ~(size_t)255; };
    size_t p = 0;
    int* off      = (int*)(ws + p); p = align256(p + (size_t)(Nn + 1) * 4);
    int* cur      = (int*)(ws + p); p = align256(p + (size_t)(Nn + 1) * 4);
    int* partials = (int*)(ws + p); p = align256(p + 256 * 4);
    u16* sorted   = (u16*)(ws + p); p = align256(p + (size_t)E * 2);
    _Float16* buf0 = (_Float16*)(ws + p); p = align256(p + (size_t)Nn * HIDN * 2);
    _Float16* buf1 = (_Float16*)(ws + p); p = align256(p + (size_t)Nn * HIDN * 2);
    _Float16* xg   = (_Float16*)(ws + p); p = align256(p + (size_t)(nTiles + 2) * 64 * HIDN * 2);
    _Float16* Wg1  = (_Float16*)(ws + p); p = align256(p + (size_t)EMB * HIDN * 2);
    _Float16* Wg2  = (_Float16*)(ws + p); p = align256(p + (size_t)HIDN * HIDN * 2);
    _Float16* Wg3  = (_Float16*)(ws + p); p = align256(p + (size_t)HIDN * EMB * 2);

    // ---- zero counters, then fused prep (cvt + hist + W packs) ----
    hipMemsetAsync(cur, 0, (size_t)Nn * 4, stream);
    const int n8 = Nn * EMB / 8;
    const int bCvtEnd  = (n8 + 255) / 256;
    const int bHistEnd = bCvtEnd + (E + 255) / 256;
    const int bW1End   = bHistEnd + (EMB / 8 * HIDN + 255) / 256;
    const int bW2End   = bW1End + (HIDN / 8 * HIDN + 255) / 256;
    const int bW3End   = bW2End + (HIDN / 8 * EMB + 255) / 256;
    prep_kernel<<<bW3End, 256, 0, stream>>>(dst, E, cur, emb, buf0, n8,
                                            W1, Wg1, W2, Wg2, W3, Wg3,
                                            bCvtEnd, bHistEnd, bW1End, bW2End, bW3End);

    // ---- CSR scan + scatter ----
    const int nScanBlocks = (Nn + 1023) / 1024;   // <= 64 supported by scan_apply
    scan_partial<<<nScanBlocks, 256, 0, stream>>>(cur, partials, Nn);
    scan_apply<<<nScanBlocks, 256, 0, stream>>>(cur, partials, nScanBlocks, off, cur, Nn, E);
    scatter_kernel<<<(E + 255) / 256, 256, 0, stream>>>(src, dst, E, cur, sorted);

    const int segBlocks = (Nn + 3) / 4;

    // ---- Layer 1: K=128 -> N=256, relu ----
    segmax_g<128><<<segBlocks, 256, 0, stream>>>(buf0, off, sorted, xg, Nn);
    gemm_g<128, 256, 1, 4, 0, 1><<<nTiles, 256, 0, stream>>>(xg, Wg1, b1, buf1, Nn);

    // ---- Layer 2: K=256 -> N=256, relu ----
    segmax_g<256><<<segBlocks, 256, 0, stream>>>(buf1, off, sorted, xg, Nn);
    gemm_g<256, 256, 1, 4, 0, 1><<<nTiles, 256, 0, stream>>>(xg, Wg2, b2, buf0, Nn);

    // ---- Layer 3: K=256 -> N=128, no relu, f32 out ----
    segmax_g<256><<<segBlocks, 256, 0, stream>>>(buf0, off, sorted, xg, Nn);
    gemm_g<256, 128, 2, 2, 1, 0><<<(nTiles + 1) / 2, 256, 0, stream>>>(xg, Wg3, b3, out, Nn);
}